// Round 4
// baseline (2406.768 us; speedup 1.0000x reference)
//
#include <hip/hip_runtime.h>
#include <stdint.h>

// Problem constants
#define T_TOK 16384
#define DH    1024
#define FF    2048
#define NE    8
#define NC    4096          // 2F
#define PADROWS 33792       // 264 * 128  (T*K rounded up with per-expert 128-padding)

typedef __attribute__((ext_vector_type(8))) __bf16 bf16x8;
typedef __attribute__((ext_vector_type(4))) float  f32x4;

__device__ __forceinline__ float bf2f(unsigned short s) {
  unsigned int u = ((unsigned int)s) << 16;
  return __builtin_bit_cast(float, u);
}
__device__ __forceinline__ unsigned short f2bf(float f) {
  unsigned int u = __builtin_bit_cast(unsigned int, f);
  u += 0x7fffu + ((u >> 16) & 1u);          // RNE
  return (unsigned short)(u >> 16);
}

// load 8 consecutive fp32 and convert to a bf16x8 MFMA fragment
__device__ __forceinline__ bf16x8 cvt8(const float* p) {
  float4 a = *(const float4*)p;
  float4 b = *(const float4*)(p + 4);
  union { bf16x8 v; unsigned short s[8]; } u;
  u.s[0] = f2bf(a.x); u.s[1] = f2bf(a.y); u.s[2] = f2bf(a.z); u.s[3] = f2bf(a.w);
  u.s[4] = f2bf(b.x); u.s[5] = f2bf(b.y); u.s[6] = f2bf(b.z); u.s[7] = f2bf(b.w);
  return u.v;
}

// interleaved column mapping: c'' in [0,4096) -> original gate_up column.
// group g = c''>>5; within: [0,16) -> gate f=g*16+wi, [16,32) -> up (orig 2048+f)
__device__ __forceinline__ int origc_gu(int c) {
  int g = c >> 5, wi = c & 31;
  return ((wi >> 4) << 11) | (g * 16 + (wi & 15));
}

// ---------------- fold kernels: W' = W + 2*A^T B^T, fp32 in -> bf16 out, TRANSPOSED [N][K] ----------------
__global__ void fold_gu_kernel(const float* __restrict__ Wg,   // [NE][DH][NC] fp32
                               const float* __restrict__ A,    // [NE][16][DH] fp32
                               const float* __restrict__ B,    // [NE][NC][16] fp32
                               unsigned short* __restrict__ Wf) // [NE][NC][DH] bf16, interleaved cols
{
  const int e = blockIdx.x, d0 = blockIdx.y * 64, c0 = blockIdx.z * 64;
  __shared__ float tile[64][65];
  __shared__ float Al[16][64];
  __shared__ float Bl[64][17];
  const int tid = threadIdx.x;
  for (int i = tid; i < 16 * 64; i += 256)
    Al[i >> 6][i & 63] = A[((size_t)e * 16 + (i >> 6)) * DH + d0 + (i & 63)];
  for (int i = tid; i < 64 * 16; i += 256) {
    int c = i >> 4, r = i & 15;
    Bl[c][r] = B[((size_t)e * NC + origc_gu(c0 + c)) * 16 + r];
  }
  __syncthreads();
  for (int pth = 0; pth < 16; pth++) {
    int idx = pth * 256 + tid;
    int dl = idx >> 6, cl = idx & 63;
    float v = Wg[((size_t)e * DH + d0 + dl) * NC + origc_gu(c0 + cl)];
    float sacc = 0.f;
#pragma unroll
    for (int r = 0; r < 16; r++) sacc += Al[r][dl] * Bl[cl][r];
    tile[dl][cl] = v + 2.f * sacc;
  }
  __syncthreads();
  for (int pth = 0; pth < 16; pth++) {
    int idx = pth * 256 + tid;
    int cl = idx >> 6, dl = idx & 63;
    Wf[((size_t)e * NC + c0 + cl) * DH + d0 + dl] = f2bf(tile[dl][cl]);
  }
}

__global__ void fold_dn_kernel(const float* __restrict__ Wd,   // [NE][FF][DH] fp32
                               const float* __restrict__ A,    // [NE][16][FF] fp32
                               const float* __restrict__ B,    // [NE][DH][16] fp32
                               unsigned short* __restrict__ Wf) // [NE][DH][FF] bf16
{
  const int e = blockIdx.x, f0 = blockIdx.y * 64, d0 = blockIdx.z * 64;
  __shared__ float tile[64][65];   // [f][d]
  __shared__ float Al[16][64];     // [r][f]
  __shared__ float Bl[64][17];     // [d][r]
  const int tid = threadIdx.x;
  for (int i = tid; i < 16 * 64; i += 256)
    Al[i >> 6][i & 63] = A[((size_t)e * 16 + (i >> 6)) * FF + f0 + (i & 63)];
  for (int i = tid; i < 64 * 16; i += 256) {
    int d = i >> 4, r = i & 15;
    Bl[d][r] = B[((size_t)e * DH + d0 + d) * 16 + r];
  }
  __syncthreads();
  for (int pth = 0; pth < 16; pth++) {
    int idx = pth * 256 + tid;
    int fl = idx >> 6, dl = idx & 63;
    float v = Wd[((size_t)e * FF + f0 + fl) * DH + d0 + dl];
    float sacc = 0.f;
#pragma unroll
    for (int r = 0; r < 16; r++) sacc += Al[r][fl] * Bl[dl][r];
    tile[fl][dl] = v + 2.f * sacc;
  }
  __syncthreads();
  for (int pth = 0; pth < 16; pth++) {
    int idx = pth * 256 + tid;
    int dl = idx >> 6, fl = idx & 63;
    Wf[((size_t)e * DH + d0 + dl) * FF + f0 + fl] = f2bf(tile[fl][dl]);
  }
}

// ---------------- routing: logits -> top-2 -> normalized weights (all fp32) ----------------
__global__ __launch_bounds__(256) void route_kernel(
    const float* __restrict__ X,
    const float* __restrict__ GW,
    const float* __restrict__ GLD,
    int* __restrict__ tokE, float* __restrict__ tokW, int* __restrict__ counts)
{
  __shared__ float gc[NE * DH];
  __shared__ int bc[NE];
  const int tid = threadIdx.x;
  if (tid < NE) bc[tid] = 0;
  for (int i = tid; i < NE * DH; i += 256) gc[i] = GW[i] + GLD[i];
  __syncthreads();
  const int w = tid >> 6, lane = tid & 63;
  for (int it = 0; it < 8; it++) {
    const int t = blockIdx.x * 32 + w * 8 + it;
    float s[NE];
#pragma unroll
    for (int e = 0; e < NE; e++) s[e] = 0.f;
#pragma unroll
    for (int i = 0; i < 8; i++) {
      const int base = 2 * lane + 128 * i;
      const float2 xv = *(const float2*)&X[(size_t)t * DH + base];
#pragma unroll
      for (int e = 0; e < NE; e++) {
        float2 g2 = *(const float2*)&gc[e * DH + base];
        s[e] += xv.x * g2.x + xv.y * g2.y;
      }
    }
#pragma unroll
    for (int e = 0; e < NE; e++) {
#pragma unroll
      for (int off = 32; off > 0; off >>= 1) s[e] += __shfl_xor(s[e], off);
    }
    int e1 = 0; float l1 = s[0];
#pragma unroll
    for (int e = 1; e < NE; e++) { if (s[e] > l1) { l1 = s[e]; e1 = e; } }
    int e2i = 0; float l2 = -3.4e38f;
#pragma unroll
    for (int e = 0; e < NE; e++) { if (e != e1 && s[e] > l2) { l2 = s[e]; e2i = e; } }
    float r = __expf(l2 - l1);
    float w0 = 1.f / (1.f + r);
    if (lane == 0) {
      tokE[2 * t] = e1; tokE[2 * t + 1] = e2i;
      tokW[2 * t] = w0; tokW[2 * t + 1] = 1.f - w0;
      atomicAdd(&bc[e1], 1); atomicAdd(&bc[e2i], 1);
    }
  }
  __syncthreads();
  if (tid < NE) atomicAdd(&counts[tid], bc[tid]);
}

__global__ void offs_kernel(const int* __restrict__ counts, int* __restrict__ offs) {
  if (threadIdx.x == 0) {
    int run = 0;
#pragma unroll
    for (int e = 0; e < NE; e++) { offs[e] = run; run += (counts[e] + 127) & ~127; }
    offs[NE] = run;
  }
}

__global__ void scatter_kernel(const int* __restrict__ tokE,
                               const int* __restrict__ offs,
                               int* __restrict__ cursor,
                               int* __restrict__ posTok,
                               int* __restrict__ posOf)
{
  const int t = blockIdx.x * 256 + threadIdx.x;
  const int lane = threadIdx.x & 63;
#pragma unroll
  for (int k = 0; k < 2; k++) {
    const int e = tokE[2 * t + k];
    int p = 0;
#pragma unroll
    for (int ei = 0; ei < NE; ei++) {
      unsigned long long mask = __ballot(e == ei);
      if (mask) {
        int leader = __ffsll((unsigned long long)mask) - 1;
        int base = 0;
        if (lane == leader) base = atomicAdd(&cursor[ei], (int)__popcll(mask));
        base = __shfl(base, leader);
        if (e == ei)
          p = offs[ei] + base + (int)__popcll(mask & ((1ull << lane) - 1ull));
      }
    }
    if (p < 0) p = 0;
    if (p >= PADROWS) p = PADROWS - 1;
    posTok[p] = t;
    posOf[2 * t + k] = p;
  }
}

// ---------------- GEMM1 (LDS-free): H = silu/up( gather(X_fp32->bf16) @ Wgu'' ) ----------------
__global__ __launch_bounds__(256) void gemm1_kernel(
    const float* __restrict__ X,              // [T][DH] fp32
    const unsigned short* __restrict__ Wgu,   // [NE][NC][DH] bf16 transposed+interleaved
    const int* __restrict__ posTok,
    const int* __restrict__ offs,
    unsigned short* __restrict__ H,           // [PADROWS][FF] bf16
    const float* __restrict__ zeroBuf)
{
  const int n0 = blockIdx.x * 128;
  const int row0 = blockIdx.y * 128;
  if (row0 >= offs[NE]) return;
  int e = 0;
#pragma unroll
  for (int i = 1; i < NE; i++) e += (row0 >= offs[i]) ? 1 : 0;
  const unsigned short* Wb = Wgu + (size_t)e * NC * DH;

  const int tid = threadIdx.x;
  const int lane = tid & 63;
  const int w = tid >> 6;
  const int wm = w >> 1, wn = w & 1;
  const int l15 = lane & 15, quad = lane >> 4;

  // A fragment row pointers (per mi): row m = l15, k-base = quad*8
  const float* aptr[4];
  int astep[4];
#pragma unroll
  for (int mi = 0; mi < 4; mi++) {
    int tok = posTok[row0 + wm * 64 + mi * 16 + l15];
    aptr[mi] = (tok >= 0) ? (X + (size_t)tok * DH + quad * 8) : zeroBuf;
    astep[mi] = (tok >= 0) ? 1 : 0;
  }
  // B fragment row pointers (per ni): output-col n = l15 within frag
  const unsigned short* bptr[4];
#pragma unroll
  for (int ni = 0; ni < 4; ni++)
    bptr[ni] = Wb + (size_t)(n0 + wn * 64 + ni * 16 + l15) * DH + quad * 8;

  f32x4 acc[4][4];
#pragma unroll
  for (int mi = 0; mi < 4; mi++)
#pragma unroll
    for (int ni = 0; ni < 4; ni++) acc[mi][ni] = (f32x4){0.f, 0.f, 0.f, 0.f};

  for (int k0 = 0; k0 < DH; k0 += 32) {
    bf16x8 af[4], bv[4];
#pragma unroll
    for (int mi = 0; mi < 4; mi++)
      af[mi] = cvt8(aptr[mi] + (size_t)(k0 * astep[mi]));
#pragma unroll
    for (int ni = 0; ni < 4; ni++)
      bv[ni] = *(const bf16x8*)(bptr[ni] + k0);
#pragma unroll
    for (int mi = 0; mi < 4; mi++)
#pragma unroll
      for (int ni = 0; ni < 4; ni++)
        acc[mi][ni] = __builtin_amdgcn_mfma_f32_16x16x32_bf16(af[mi], bv[ni], acc[mi][ni], 0, 0, 0);
  }

  const int rowb = row0 + wm * 64;
#pragma unroll
  for (int mi = 0; mi < 4; mi++) {
#pragma unroll
    for (int p = 0; p < 2; p++) {   // (ni=2p -> gate, ni=2p+1 -> up) same lane, same f
      f32x4 g = acc[mi][2 * p], u = acc[mi][2 * p + 1];
      int f = (n0 >> 1) + wn * 32 + p * 16 + l15;
#pragma unroll
      for (int r = 0; r < 4; r++) {
        int row = rowb + mi * 16 + quad * 4 + r;
        float gv = g[r];
        float hv = (gv / (1.f + __expf(-gv))) * u[r];
        H[(size_t)row * FF + f] = f2bf(hv);
      }
    }
  }
}

// ---------------- GEMM2 (LDS-free): Y = H @ Wdn'' ----------------
__global__ __launch_bounds__(256) void gemm2_kernel(
    const unsigned short* __restrict__ H,
    const unsigned short* __restrict__ Wdn,   // [NE][DH][FF] bf16 transposed
    const int* __restrict__ offs,
    unsigned short* __restrict__ Y)           // [PADROWS][DH] bf16
{
  const int n0 = blockIdx.x * 128;
  const int row0 = blockIdx.y * 128;
  if (row0 >= offs[NE]) return;
  int e = 0;
#pragma unroll
  for (int i = 1; i < NE; i++) e += (row0 >= offs[i]) ? 1 : 0;
  const unsigned short* Wb = Wdn + (size_t)e * DH * FF;

  const int tid = threadIdx.x;
  const int lane = tid & 63;
  const int w = tid >> 6;
  const int wm = w >> 1, wn = w & 1;
  const int l15 = lane & 15, quad = lane >> 4;

  const unsigned short* aptr[4];
#pragma unroll
  for (int mi = 0; mi < 4; mi++)
    aptr[mi] = H + (size_t)(row0 + wm * 64 + mi * 16 + l15) * FF + quad * 8;
  const unsigned short* bptr[4];
#pragma unroll
  for (int ni = 0; ni < 4; ni++)
    bptr[ni] = Wb + (size_t)(n0 + wn * 64 + ni * 16 + l15) * FF + quad * 8;

  f32x4 acc[4][4];
#pragma unroll
  for (int mi = 0; mi < 4; mi++)
#pragma unroll
    for (int ni = 0; ni < 4; ni++) acc[mi][ni] = (f32x4){0.f, 0.f, 0.f, 0.f};

  for (int k0 = 0; k0 < FF; k0 += 32) {
    bf16x8 af[4], bv[4];
#pragma unroll
    for (int mi = 0; mi < 4; mi++)
      af[mi] = *(const bf16x8*)(aptr[mi] + k0);
#pragma unroll
    for (int ni = 0; ni < 4; ni++)
      bv[ni] = *(const bf16x8*)(bptr[ni] + k0);
#pragma unroll
    for (int mi = 0; mi < 4; mi++)
#pragma unroll
      for (int ni = 0; ni < 4; ni++)
        acc[mi][ni] = __builtin_amdgcn_mfma_f32_16x16x32_bf16(af[mi], bv[ni], acc[mi][ni], 0, 0, 0);
  }

#pragma unroll
  for (int mi = 0; mi < 4; mi++)
#pragma unroll
    for (int ni = 0; ni < 4; ni++) {
      int col = n0 + wn * 64 + ni * 16 + l15;
#pragma unroll
      for (int r = 0; r < 4; r++) {
        int row = row0 + wm * 64 + mi * 16 + quad * 4 + r;
        Y[(size_t)row * DH + col] = f2bf(acc[mi][ni][r]);
      }
    }
}

// ---------------- combine: out[t] = w0*Y[p0] + w1*Y[p1]  (bf16 Y -> fp32 out) ----------------
__global__ void combine_kernel(const unsigned short* __restrict__ Y,
                               const int* __restrict__ posOf,
                               const float* __restrict__ tokW,
                               float* __restrict__ out)
{
  int idx = blockIdx.x * 256 + threadIdx.x;
  int t = idx >> 7;
  int c = (idx & 127) * 8;
  int p0 = posOf[2 * t], p1 = posOf[2 * t + 1];
  float w0 = tokW[2 * t], w1 = tokW[2 * t + 1];
  const uint4 a = *(const uint4*)&Y[(size_t)p0 * DH + c];
  const uint4 b = *(const uint4*)&Y[(size_t)p1 * DH + c];
  const unsigned* ap = (const unsigned*)&a;
  const unsigned* bp = (const unsigned*)&b;
  float4 o0, o1;
  float* op = (float*)&o0;
#pragma unroll
  for (int i = 0; i < 4; i++) {
    float a0 = bf2f((unsigned short)(ap[i] & 0xffff)), a1 = bf2f((unsigned short)(ap[i] >> 16));
    float b0 = bf2f((unsigned short)(bp[i] & 0xffff)), b1 = bf2f((unsigned short)(bp[i] >> 16));
    float r0 = w0 * a0 + w1 * b0;
    float r1 = w0 * a1 + w1 * b1;
    if (i < 2) { ((float*)&o0)[2 * i] = r0; ((float*)&o0)[2 * i + 1] = r1; }
    else       { ((float*)&o1)[2 * (i - 2)] = r0; ((float*)&o1)[2 * (i - 2) + 1] = r1; }
  }
  (void)op;
  *(float4*)&out[(size_t)t * DH + c]     = o0;
  *(float4*)&out[(size_t)t * DH + c + 4] = o1;
}

extern "C" void kernel_launch(void* const* d_in, const int* in_sizes, int n_in,
                              void* d_out, int out_size, void* d_ws, size_t ws_size,
                              hipStream_t stream)
{
  const float* X   = (const float*)d_in[0];
  const float* GW  = (const float*)d_in[1];
  const float* GLD = (const float*)d_in[2];
  const float* GUP = (const float*)d_in[3];
  const float* DNP = (const float*)d_in[4];
  const float* GUA = (const float*)d_in[5];
  const float* GUB = (const float*)d_in[6];
  const float* DNA = (const float*)d_in[7];
  const float* DNB = (const float*)d_in[8];
  float* OUT = (float*)d_out;

  char* p = (char*)d_ws;
  unsigned short* Wguf = (unsigned short*)p; p += (size_t)NE * NC * DH * 2;   // 64 MiB
  unsigned short* Wdnf = (unsigned short*)p; p += (size_t)NE * DH * FF * 2;   // 32 MiB
  unsigned short* H    = (unsigned short*)p; p += (size_t)PADROWS * FF * 2;   // 132 MiB
  unsigned short* Y    = (unsigned short*)p; p += (size_t)PADROWS * DH * 2;   // 66 MiB
  int*   posTok = (int*)p;   p += (size_t)PADROWS * 4;
  int*   posOf  = (int*)p;   p += (size_t)T_TOK * 2 * 4;
  int*   tokE   = (int*)p;   p += (size_t)T_TOK * 2 * 4;
  float* tokW   = (float*)p; p += (size_t)T_TOK * 2 * 4;
  int*   counts = (int*)p;   p += 32;
  int*   cursor = (int*)p;   p += 32;
  int*   offs   = (int*)p;   p += 64;
  float* zeroBuf = (float*)p; p += 256;
  if ((size_t)(p - (char*)d_ws) > ws_size) return;  // workspace too small

  hipMemsetAsync(counts, 0, 32 + 32 + 64 + 256, stream);   // counts+cursor+offs+zeroBuf
  hipMemsetAsync(posTok, 0xFF, (size_t)PADROWS * 4, stream);

  fold_gu_kernel<<<dim3(NE, DH / 64, NC / 64), 256, 0, stream>>>(GUP, GUA, GUB, Wguf);
  fold_dn_kernel<<<dim3(NE, FF / 64, DH / 64), 256, 0, stream>>>(DNP, DNA, DNB, Wdnf);
  route_kernel<<<T_TOK / 32, 256, 0, stream>>>(X, GW, GLD, tokE, tokW, counts);
  offs_kernel<<<1, 64, 0, stream>>>(counts, offs);
  scatter_kernel<<<T_TOK / 256, 256, 0, stream>>>(tokE, offs, cursor, posTok, posOf);
  gemm1_kernel<<<dim3(NC / 128, PADROWS / 128), 256, 0, stream>>>(X, Wguf, posTok, offs, H, zeroBuf);
  gemm2_kernel<<<dim3(DH / 128, PADROWS / 128), 256, 0, stream>>>(H, Wdnf, offs, Y);
  combine_kernel<<<(T_TOK * DH / 8) / 256, 256, 0, stream>>>(Y, posOf, tokW, OUT);
}